// Round 10
// baseline (70.669 us; speedup 1.0000x reference)
//
#include <hip/hip_runtime.h>
#include <hip/hip_bf16.h>
#include <math.h>

#define BSZ   4096
#define F     26
#define VOC   100000
#define D     64
#define AD    64
#define ND    13
#define FEA   77
#define NPAIR 325
#define NPAD  336    // 21 M-tiles of 16
#define MT    21
#define EP    68     // e row stride in floats (272B, float4-aligned slices)
#define H1    256
#define H2    128
#define H3    64
#define EPSF  1e-5f

typedef __attribute__((ext_vector_type(8))) short short8;
typedef __attribute__((ext_vector_type(4))) float f32x4;

union FragU { short8 s; unsigned int u[4]; };

__device__ __forceinline__ unsigned int pk2bf(float a, float b) {
  __hip_bfloat162 h = __float22bfloat162_rn(make_float2(a, b));  // v_cvt_pk_bf16_f32
  return *reinterpret_cast<unsigned int*>(&h);
}
__device__ __forceinline__ unsigned short f2bf(float f) {
  unsigned int u = __float_as_uint(f);
  u += 0x7fffu + ((u >> 16) & 1u);
  return (unsigned short)(u >> 16);
}
// VALU-pipe cross-lane add via DPP
template<int CTRL>
__device__ __forceinline__ float dpp_add(float x) {
  int xi = __builtin_bit_cast(int, x);
  int yi = __builtin_amdgcn_update_dpp(xi, xi, CTRL, 0xf, 0xf, false);
  return x + __builtin_bit_cast(float, yi);
}
// full 16-lane-row sum (all lanes get total): xor1, xor2, ror4, ror8
__device__ __forceinline__ float row16_sum(float x) {
  x = dpp_add<0xB1>(x);
  x = dpp_add<0x4E>(x);
  x = dpp_add<0x124>(x);
  x = dpp_add<0x128>(x);
  return x;
}
// broadcast lane L of v to all lanes (compile-time L under full unroll)
__device__ __forceinline__ float bcast_lane(float v, int l) {
  return __builtin_bit_cast(float,
      __builtin_amdgcn_readlane(__builtin_bit_cast(int, v), l));
}

// ------- K1: attention + BN-stats. One WAVE per batch row, 1 barrier. ------
__global__ __launch_bounds__(256, 4) void k_attn(
    const int* __restrict__ sx, const float* __restrict__ dx,
    const float* __restrict__ emb, const float* __restrict__ attW,
    const float* __restrict__ attb, const float* __restrict__ attdW,
    const float* __restrict__ attdb, float* __restrict__ x,
    float* __restrict__ partS, float* __restrict__ partQ)
{
  __shared__ __align__(16) float e_all[4][27 * EP];   // f32 e, row 26 = zeros
  __shared__ __align__(16) float sc_all[4][NPAD];
  __shared__ float xblk[4][80];
  __shared__ unsigned short pt[NPAD];

  const int t    = threadIdx.x;
  const int lane = t & 63;
  const int wv   = t >> 6;
  const int b    = __builtin_amdgcn_readfirstlane(blockIdx.x * 4 + wv);

  // pair table (f1 | f2<<8) for the score phase; pads -> zero-row 26
  for (int p = t; p < NPAD; p += 256) {
    int f1 = 26, f2 = 26;
    if (p < NPAIR) {
      int i = 0, rem = p;
      while (rem >= F - 1 - i) { rem -= F - 1 - i; ++i; }
      f1 = i; f2 = i + 1 + rem;
    }
    pt[p] = (unsigned short)(f1 | (f2 << 8));
  }

  float* e_w  = e_all[wv];
  float* sc_w = sc_all[wv];

  // gather straight to LDS (batched loads for ILP)
  {
    const int* sxb = sx + b * F;
    int rows[F];
    #pragma unroll
    for (int f = 0; f < F; ++f) rows[f] = sxb[f];   // wave-uniform s-loads
    float vf[F];
    #pragma unroll
    for (int f = 0; f < F; ++f)
      vf[f] = emb[((size_t)f * VOC + rows[f]) * D + lane];  // coalesced 256B
    #pragma unroll
    for (int f = 0; f < F; ++f) e_w[f * EP + lane] = vf[f];
    e_w[26 * EP + lane] = 0.f;                      // zero pad row
  }

  // B fragments (attW columns) + biases — global, L1/L2-resident
  short8 bfrag[2][4];
  float bj[4], dwj[4];
  {
    const int kb = (lane >> 4) * 8;
    const int cl = lane & 15;
    #pragma unroll
    for (int kk = 0; kk < 2; ++kk)
      #pragma unroll
      for (int n = 0; n < 4; ++n)
        #pragma unroll
        for (int j = 0; j < 8; ++j) {
          int k = kk * 32 + kb + j;
          bfrag[kk][n][j] = (short)f2bf(attW[k * AD + n * 16 + cl]);
        }
    #pragma unroll
    for (int n = 0; n < 4; ++n) {
      bj[n]  = attb[n * 16 + cl];
      dwj[n] = attdW[n * 16 + cl];
    }
  }
  const float db0 = attdb[0];

  __syncthreads();   // pt table (e_w/sc_w are wave-private)

  // ---- phase 1: score GEMM, 21 M-tiles (packed-f32 operand prep) ----
  const int row16 = lane & 15;
  const int kgrp  = lane >> 4;
  const int k0    = kgrp * 8;
  const f32x4 zero4 = {0.f, 0.f, 0.f, 0.f};
  for (int m = 0; m < MT; ++m) {
    const int prow = m * 16 + row16;
    const unsigned short pp = pt[prow];
    const float* r1 = &e_w[(pp & 0xff) * EP];
    const float* r2 = &e_w[(pp >> 8) * EP];
    f32x4 xv0 = *(const f32x4*)&r1[k0];
    f32x4 xv1 = *(const f32x4*)&r1[k0 + 4];
    f32x4 yv0 = *(const f32x4*)&r2[k0];
    f32x4 yv1 = *(const f32x4*)&r2[k0 + 4];
    f32x4 xv2 = *(const f32x4*)&r1[32 + k0];
    f32x4 xv3 = *(const f32x4*)&r1[32 + k0 + 4];
    f32x4 yv2 = *(const f32x4*)&r2[32 + k0];
    f32x4 yv3 = *(const f32x4*)&r2[32 + k0 + 4];
    f32x4 pa = xv0 * yv0;   // v_pk_mul_f32
    f32x4 pb = xv1 * yv1;
    f32x4 pc = xv2 * yv2;
    f32x4 pd = xv3 * yv3;
    FragU a0, a1;
    a0.u[0] = pk2bf(pa[0], pa[1]); a0.u[1] = pk2bf(pa[2], pa[3]);
    a0.u[2] = pk2bf(pb[0], pb[1]); a0.u[3] = pk2bf(pb[2], pb[3]);
    a1.u[0] = pk2bf(pc[0], pc[1]); a1.u[1] = pk2bf(pc[2], pc[3]);
    a1.u[2] = pk2bf(pd[0], pd[1]); a1.u[3] = pk2bf(pd[2], pd[3]);

    f32x4 acc[4];
    #pragma unroll
    for (int n = 0; n < 4; ++n) {
      acc[n] = __builtin_amdgcn_mfma_f32_16x16x32_bf16(a0.s, bfrag[0][n], zero4, 0, 0, 0);
      acc[n] = __builtin_amdgcn_mfma_f32_16x16x32_bf16(a1.s, bfrag[1][n], acc[n], 0, 0, 0);
    }
    // epilogue: vale[r] = sum_n relu(acc[n][r]+bj[n])*dwj[n] (packed)
    f32x4 vale = zero4;
    #pragma unroll
    for (int n = 0; n < 4; ++n) {
      f32x4 rl = __builtin_elementwise_max(acc[n] + bj[n], zero4);
      vale = rl * dwj[n] + vale;   // v_pk_fma_f32
    }
    float s0 = row16_sum(vale[0]) + db0;
    float s1 = row16_sum(vale[1]) + db0;
    float s2 = row16_sum(vale[2]) + db0;
    float s3 = row16_sum(vale[3]) + db0;
    if (row16 == 0) {
      float4 o = {s0, s1, s2, s3};
      *(float4*)&sc_w[m * 16 + kgrp * 4] = o;
    }
  }

  // ---- phase 2: in-wave softmax over 325 scores ----
  float sv[6], ev[6];
  float mx = -1e30f;
  #pragma unroll
  for (int i = 0; i < 6; ++i) {
    int idx = lane + 64 * i;
    sv[i] = (idx < NPAIR) ? sc_w[idx] : -1e30f;
    mx = fmaxf(mx, sv[i]);
  }
  #pragma unroll
  for (int off = 32; off; off >>= 1) mx = fmaxf(mx, __shfl_xor(mx, off));
  float s = 0.f;
  #pragma unroll
  for (int i = 0; i < 6; ++i) {
    int idx = lane + 64 * i;
    ev[i] = (idx < NPAIR) ? __expf(sv[i] - mx) : 0.f;
    s += ev[i];
  }
  #pragma unroll
  for (int off = 32; off; off >>= 1) s += __shfl_xor(s, off);
  const float invZ = 1.f / s;

  // ---- phase 3: PV in registers; reload e from LDS (bfrag now dead) ----
  float ef[F];
  #pragma unroll
  for (int f = 0; f < F; ++f) ef[f] = e_w[f * EP + lane];

  float pa0 = 0.f, pa1 = 0.f, pa2 = 0.f, pa3 = 0.f;
  {
    int p = 0;
    #pragma unroll
    for (int f1 = 0; f1 < F - 1; ++f1) {
      #pragma unroll
      for (int f2 = f1 + 1; f2 < F; ++f2) {
        const float w = bcast_lane(ev[p >> 6], p & 63);
        const float prod = ef[f1] * ef[f2];
        if ((p & 3) == 0)      pa0 = fmaf(w, prod, pa0);
        else if ((p & 3) == 1) pa1 = fmaf(w, prod, pa1);
        else if ((p & 3) == 2) pa2 = fmaf(w, prod, pa2);
        else                   pa3 = fmaf(w, prod, pa3);
        ++p;
      }
    }
  }
  const float att = ((pa0 + pa1) + (pa2 + pa3)) * invZ;

  // store x (coalesced) + stage row in LDS for BN stats
  x[(size_t)b * FEA + lane] = att;
  xblk[wv][lane] = att;
  if (lane < ND) {
    float dv = dx[b * ND + lane];
    x[(size_t)b * FEA + D + lane] = dv;
    xblk[wv][D + lane] = dv;
  }
  __syncthreads();

  // ---- BN partial stats: one thread per feature, 4 rows, bucketed atomics --
  if (t < FEA) {
    float x0 = xblk[0][t], x1 = xblk[1][t], x2 = xblk[2][t], x3 = xblk[3][t];
    float sS = (x0 + x1) + (x2 + x3);
    float sQ = (x0 * x0 + x1 * x1) + (x2 * x2 + x3 * x3);
    const int bkt = (blockIdx.x & 7) * 80 + t;
    atomicAdd(&partS[bkt], sS);
    atomicAdd(&partQ[bkt], sQ);
  }
}

// -- K2: MLP, 4 rows/block, activations in lane-distributed regs + readlane --
__global__ __launch_bounds__(256) void k_mlp(
    const float* __restrict__ x,
    const float* __restrict__ partS, const float* __restrict__ partQ,
    const float* __restrict__ gamma, const float* __restrict__ beta,
    const float* __restrict__ w1, const float* __restrict__ b1,
    const float* __restrict__ w2, const float* __restrict__ b2,
    const float* __restrict__ w3, const float* __restrict__ b3,
    const float* __restrict__ wf, const float* __restrict__ bf,
    float* __restrict__ out)
{
  __shared__ float h1s[4][H1];   // 4 KB
  __shared__ float h2s[4][H2];   // 2 KB
  const int t    = threadIdx.x;
  const int lane = t & 63;
  const int wvid = t >> 6;
  const int b0   = blockIdx.x * 4;

  // BN coefficients for features f0=lane, f1=64+lane (per-lane, no LDS)
  float scl0, sh0, scl1 = 0.f, sh1 = 0.f;
  {
    float S0 = 0.f, Q0 = 0.f;
    #pragma unroll
    for (int k = 0; k < 8; ++k) {
      S0 += partS[k * 80 + lane];
      Q0 += partQ[k * 80 + lane];
    }
    float mu0  = S0 * (1.f / BSZ);
    float var0 = Q0 * (1.f / BSZ) - mu0 * mu0;
    scl0 = gamma[lane] * rsqrtf(var0 + EPSF);
    sh0  = beta[lane] - mu0 * scl0;
    if (lane < ND) {
      float S1 = 0.f, Q1 = 0.f;
      #pragma unroll
      for (int k = 0; k < 8; ++k) {
        S1 += partS[k * 80 + 64 + lane];
        Q1 += partQ[k * 80 + 64 + lane];
      }
      float mu1  = S1 * (1.f / BSZ);
      float var1 = Q1 * (1.f / BSZ) - mu1 * mu1;
      scl1 = gamma[64 + lane] * rsqrtf(var1 + EPSF);
      sh1  = beta[64 + lane] - mu1 * scl1;
    }
  }

  // xn lane-distributed: xa[r] = xn[r][lane], xb[r] = xn[r][64+lane] (lane<13)
  float xa[4], xb[4];
  #pragma unroll
  for (int r = 0; r < 4; ++r) {
    xa[r] = x[(size_t)(b0 + r) * FEA + lane] * scl0 + sh0;
    xb[r] = (lane < ND) ? x[(size_t)(b0 + r) * FEA + 64 + lane] * scl1 + sh1 : 0.f;
  }

  // ---- L1: 77 -> 256. thread t = out col; readlane broadcasts, no LDS ----
  {
    float acc[4];
    const float bb = b1[t];
    #pragma unroll
    for (int r = 0; r < 4; ++r) acc[r] = bb;
    #pragma unroll
    for (int d0 = 0; d0 < 72; d0 += 8) {
      float wl[8];
      #pragma unroll
      for (int u = 0; u < 8; ++u) wl[u] = w1[(d0 + u) * H1 + t];
      #pragma unroll
      for (int u = 0; u < 8; ++u) {
        const int d = d0 + u;
        #pragma unroll
        for (int r = 0; r < 4; ++r) {
          const float sv = (d < 64) ? bcast_lane(xa[r], d) : bcast_lane(xb[r], d - 64);
          acc[r] = fmaf(sv, wl[u], acc[r]);
        }
      }
    }
    {  // tail d = 72..76
      float wl[5];
      #pragma unroll
      for (int u = 0; u < 5; ++u) wl[u] = w1[(72 + u) * H1 + t];
      #pragma unroll
      for (int u = 0; u < 5; ++u) {
        #pragma unroll
        for (int r = 0; r < 4; ++r) {
          const float sv = bcast_lane(xb[r], 8 + u);
          acc[r] = fmaf(sv, wl[u], acc[r]);
        }
      }
    }
    #pragma unroll
    for (int r = 0; r < 4; ++r) h1s[r][t] = fmaxf(acc[r], 0.f);
  }
  __syncthreads();

  // ---- L2: 256 -> 128. j = t&127, 2 rows; h1 lane-distributed copies ----
  const int j2 = t & 127;
  const int rb = (t >> 7) * 2;
  {
    float h1a[4], h1b[4];
    #pragma unroll
    for (int k = 0; k < 4; ++k) {
      h1a[k] = h1s[rb + 0][lane + 64 * k];
      h1b[k] = h1s[rb + 1][lane + 64 * k];
    }
    float acc0 = b2[j2], acc1 = acc0;
    #pragma unroll
    for (int c0 = 0; c0 < H1; c0 += 8) {
      float wl[8];
      #pragma unroll
      for (int u = 0; u < 8; ++u) wl[u] = w2[(c0 + u) * H2 + j2];
      #pragma unroll
      for (int u = 0; u < 8; ++u) {
        const int c = c0 + u;
        acc0 = fmaf(bcast_lane(h1a[c >> 6], c & 63), wl[u], acc0);
        acc1 = fmaf(bcast_lane(h1b[c >> 6], c & 63), wl[u], acc1);
      }
    }
    h2s[rb + 0][j2] = fmaxf(acc0, 0.f);
    h2s[rb + 1][j2] = fmaxf(acc1, 0.f);
  }
  __syncthreads();

  // ---- L3: 128 -> 64. wave w = row, lane = out col ----
  float h3v;
  {
    float h2a[2];
    h2a[0] = h2s[wvid][lane];
    h2a[1] = h2s[wvid][64 + lane];
    float acc = b3[lane];
    #pragma unroll
    for (int c0 = 0; c0 < H2; c0 += 8) {
      float wl[8];
      #pragma unroll
      for (int u = 0; u < 8; ++u) wl[u] = w3[(c0 + u) * H3 + lane];
      #pragma unroll
      for (int u = 0; u < 8; ++u) {
        const int c = c0 + u;
        acc = fmaf(bcast_lane(h2a[c >> 6], c & 63), wl[u], acc);
      }
    }
    h3v = fmaxf(acc, 0.f);
  }

  // ---- final: 64 -> 1 + sigmoid, in-wave reduce ----
  {
    float v = h3v * wf[lane];
    #pragma unroll
    for (int off = 32; off; off >>= 1) v += __shfl_xor(v, off);
    if (lane == 0)
      out[b0 + wvid] = 1.f / (1.f + __expf(-(v + bf[0])));
  }
}

extern "C" void kernel_launch(void* const* d_in, const int* in_sizes, int n_in,
                              void* d_out, int out_size, void* d_ws, size_t ws_size,
                              hipStream_t stream) {
  const int*   sx    = (const int*)  d_in[0];
  const float* dx    = (const float*)d_in[1];
  const float* emb   = (const float*)d_in[2];
  const float* attW  = (const float*)d_in[3];
  const float* attb  = (const float*)d_in[4];
  const float* attdW = (const float*)d_in[5];
  const float* attdb = (const float*)d_in[6];
  const float* gamma = (const float*)d_in[7];
  const float* beta  = (const float*)d_in[8];
  const float* w1    = (const float*)d_in[9];
  const float* b1    = (const float*)d_in[10];
  const float* w2    = (const float*)d_in[11];
  const float* b2    = (const float*)d_in[12];
  const float* w3    = (const float*)d_in[13];
  const float* b3    = (const float*)d_in[14];
  const float* wf    = (const float*)d_in[15];
  const float* bf    = (const float*)d_in[16];
  float* out = (float*)d_out;

  float* x     = (float*)d_ws;                    // B*FEA
  float* partS = x + (size_t)BSZ * FEA;           // 8*80
  float* partQ = partS + 8 * 80;                  // 8*80

  hipMemsetAsync(partS, 0, 2 * 8 * 80 * sizeof(float), stream);
  k_attn<<<BSZ / 4, 256, 0, stream>>>(sx, dx, emb, attW, attb, attdW, attdb,
                                      x, partS, partQ);
  k_mlp<<<BSZ / 4, 256, 0, stream>>>(x, partS, partQ, gamma, beta,
                                     w1, b1, w2, b2, w3, b3, wf, bf, out);
}

// Round 11
// 65.293 us; speedup vs baseline: 1.0823x; 1.0823x over previous
//
#include <hip/hip_runtime.h>
#include <hip/hip_bf16.h>
#include <math.h>

#define BSZ   4096
#define F     26
#define VOC   100000
#define D     64
#define AD    64
#define ND    13
#define FEA   77
#define NPAIR 325
#define NPAD  336    // 21 M-tiles of 16
#define MT    21
#define EP    68     // e row stride in floats (272B, float4-aligned slices)
#define H1    256
#define H2    128
#define H3    64
#define EPSF  1e-5f
#define MROW  4      // k_mlp rows per block (1024 blocks)

typedef __attribute__((ext_vector_type(8))) short short8;
typedef __attribute__((ext_vector_type(4))) float f32x4;

union FragU { short8 s; unsigned int u[4]; };

__device__ __forceinline__ unsigned int pk2bf(float a, float b) {
  __hip_bfloat162 h = __float22bfloat162_rn(make_float2(a, b));  // v_cvt_pk_bf16_f32
  return *reinterpret_cast<unsigned int*>(&h);
}
__device__ __forceinline__ unsigned short f2bf(float f) {
  unsigned int u = __float_as_uint(f);
  u += 0x7fffu + ((u >> 16) & 1u);
  return (unsigned short)(u >> 16);
}
// VALU-pipe cross-lane add via DPP
template<int CTRL>
__device__ __forceinline__ float dpp_add(float x) {
  int xi = __builtin_bit_cast(int, x);
  int yi = __builtin_amdgcn_update_dpp(xi, xi, CTRL, 0xf, 0xf, false);
  return x + __builtin_bit_cast(float, yi);
}
// full 16-lane-row sum (all lanes get total): xor1, xor2, ror4, ror8
__device__ __forceinline__ float row16_sum(float x) {
  x = dpp_add<0xB1>(x);
  x = dpp_add<0x4E>(x);
  x = dpp_add<0x124>(x);
  x = dpp_add<0x128>(x);
  return x;
}
// broadcast lane L of v to all lanes (compile-time L under full unroll)
__device__ __forceinline__ float bcast_lane(float v, int l) {
  return __builtin_bit_cast(float,
      __builtin_amdgcn_readlane(__builtin_bit_cast(int, v), l));
}

// ------- K1: attention + BN-stats. One WAVE per batch row, 1 barrier. ------
__global__ __launch_bounds__(256, 4) void k_attn(
    const int* __restrict__ sx, const float* __restrict__ dx,
    const float* __restrict__ emb, const float* __restrict__ attW,
    const float* __restrict__ attb, const float* __restrict__ attdW,
    const float* __restrict__ attdb, float* __restrict__ x,
    float* __restrict__ partS, float* __restrict__ partQ)
{
  __shared__ __align__(16) float e_all[4][27 * EP];   // f32 e, row 26 = zeros
  __shared__ __align__(16) float sc_all[4][NPAD];
  __shared__ float xblk[4][80];
  __shared__ unsigned short pt[NPAD];

  const int t    = threadIdx.x;
  const int lane = t & 63;
  const int wv   = t >> 6;
  const int b    = __builtin_amdgcn_readfirstlane(blockIdx.x * 4 + wv);

  // pair table (f1 | f2<<8) for the score phase; pads -> zero-row 26
  for (int p = t; p < NPAD; p += 256) {
    int f1 = 26, f2 = 26;
    if (p < NPAIR) {
      int i = 0, rem = p;
      while (rem >= F - 1 - i) { rem -= F - 1 - i; ++i; }
      f1 = i; f2 = i + 1 + rem;
    }
    pt[p] = (unsigned short)(f1 | (f2 << 8));
  }

  float* e_w  = e_all[wv];
  float* sc_w = sc_all[wv];

  // gather straight to LDS (batched loads for ILP)
  {
    const int* sxb = sx + b * F;
    int rows[F];
    #pragma unroll
    for (int f = 0; f < F; ++f) rows[f] = sxb[f];   // wave-uniform s-loads
    float vf[F];
    #pragma unroll
    for (int f = 0; f < F; ++f)
      vf[f] = emb[((size_t)f * VOC + rows[f]) * D + lane];  // coalesced 256B
    #pragma unroll
    for (int f = 0; f < F; ++f) e_w[f * EP + lane] = vf[f];
    e_w[26 * EP + lane] = 0.f;                      // zero pad row
  }

  // B fragments (attW columns) + biases — global, L1/L2-resident
  short8 bfrag[2][4];
  float bj[4], dwj[4];
  {
    const int kb = (lane >> 4) * 8;
    const int cl = lane & 15;
    #pragma unroll
    for (int kk = 0; kk < 2; ++kk)
      #pragma unroll
      for (int n = 0; n < 4; ++n)
        #pragma unroll
        for (int j = 0; j < 8; ++j) {
          int k = kk * 32 + kb + j;
          bfrag[kk][n][j] = (short)f2bf(attW[k * AD + n * 16 + cl]);
        }
    #pragma unroll
    for (int n = 0; n < 4; ++n) {
      bj[n]  = attb[n * 16 + cl];
      dwj[n] = attdW[n * 16 + cl];
    }
  }
  const float db0 = attdb[0];

  __syncthreads();   // pt table (e_w/sc_w are wave-private)

  // ---- phase 1: score GEMM, 21 M-tiles (packed-f32 prep, 2-deep ILP) ----
  const int row16 = lane & 15;
  const int kgrp  = lane >> 4;
  const int k0    = kgrp * 8;
  const f32x4 zero4 = {0.f, 0.f, 0.f, 0.f};
  #pragma unroll 2
  for (int m = 0; m < MT; ++m) {
    const int prow = m * 16 + row16;
    const unsigned short pp = pt[prow];
    const float* r1 = &e_w[(pp & 0xff) * EP];
    const float* r2 = &e_w[(pp >> 8) * EP];
    f32x4 xv0 = *(const f32x4*)&r1[k0];
    f32x4 xv1 = *(const f32x4*)&r1[k0 + 4];
    f32x4 yv0 = *(const f32x4*)&r2[k0];
    f32x4 yv1 = *(const f32x4*)&r2[k0 + 4];
    f32x4 xv2 = *(const f32x4*)&r1[32 + k0];
    f32x4 xv3 = *(const f32x4*)&r1[32 + k0 + 4];
    f32x4 yv2 = *(const f32x4*)&r2[32 + k0];
    f32x4 yv3 = *(const f32x4*)&r2[32 + k0 + 4];
    f32x4 pa = xv0 * yv0;   // v_pk_mul_f32
    f32x4 pb = xv1 * yv1;
    f32x4 pc = xv2 * yv2;
    f32x4 pd = xv3 * yv3;
    FragU a0, a1;
    a0.u[0] = pk2bf(pa[0], pa[1]); a0.u[1] = pk2bf(pa[2], pa[3]);
    a0.u[2] = pk2bf(pb[0], pb[1]); a0.u[3] = pk2bf(pb[2], pb[3]);
    a1.u[0] = pk2bf(pc[0], pc[1]); a1.u[1] = pk2bf(pc[2], pc[3]);
    a1.u[2] = pk2bf(pd[0], pd[1]); a1.u[3] = pk2bf(pd[2], pd[3]);

    f32x4 acc[4];
    #pragma unroll
    for (int n = 0; n < 4; ++n) {
      acc[n] = __builtin_amdgcn_mfma_f32_16x16x32_bf16(a0.s, bfrag[0][n], zero4, 0, 0, 0);
      acc[n] = __builtin_amdgcn_mfma_f32_16x16x32_bf16(a1.s, bfrag[1][n], acc[n], 0, 0, 0);
    }
    // epilogue: vale[r] = sum_n relu(acc[n][r]+bj[n])*dwj[n] (packed)
    f32x4 vale = zero4;
    #pragma unroll
    for (int n = 0; n < 4; ++n) {
      f32x4 rl = __builtin_elementwise_max(acc[n] + bj[n], zero4);
      vale = rl * dwj[n] + vale;   // v_pk_fma_f32
    }
    float s0 = row16_sum(vale[0]) + db0;
    float s1 = row16_sum(vale[1]) + db0;
    float s2 = row16_sum(vale[2]) + db0;
    float s3 = row16_sum(vale[3]) + db0;
    if (row16 == 0) {
      float4 o = {s0, s1, s2, s3};
      *(float4*)&sc_w[m * 16 + kgrp * 4] = o;
    }
  }

  // ---- phase 2: in-wave softmax over 325 scores ----
  float sv[6], ev[6];
  float mx = -1e30f;
  #pragma unroll
  for (int i = 0; i < 6; ++i) {
    int idx = lane + 64 * i;
    sv[i] = (idx < NPAIR) ? sc_w[idx] : -1e30f;
    mx = fmaxf(mx, sv[i]);
  }
  #pragma unroll
  for (int off = 32; off; off >>= 1) mx = fmaxf(mx, __shfl_xor(mx, off));
  float s = 0.f;
  #pragma unroll
  for (int i = 0; i < 6; ++i) {
    int idx = lane + 64 * i;
    ev[i] = (idx < NPAIR) ? __expf(sv[i] - mx) : 0.f;
    s += ev[i];
  }
  #pragma unroll
  for (int off = 32; off; off >>= 1) s += __shfl_xor(s, off);
  const float invZ = 1.f / s;

  // ---- phase 3: PV in registers; reload e from LDS (bfrag now dead) ----
  float ef[F];
  #pragma unroll
  for (int f = 0; f < F; ++f) ef[f] = e_w[f * EP + lane];

  float pa0 = 0.f, pa1 = 0.f, pa2 = 0.f, pa3 = 0.f;
  {
    int p = 0;
    #pragma unroll
    for (int f1 = 0; f1 < F - 1; ++f1) {
      #pragma unroll
      for (int f2 = f1 + 1; f2 < F; ++f2) {
        const float w = bcast_lane(ev[p >> 6], p & 63);
        const float prod = ef[f1] * ef[f2];
        if ((p & 3) == 0)      pa0 = fmaf(w, prod, pa0);
        else if ((p & 3) == 1) pa1 = fmaf(w, prod, pa1);
        else if ((p & 3) == 2) pa2 = fmaf(w, prod, pa2);
        else                   pa3 = fmaf(w, prod, pa3);
        ++p;
      }
    }
  }
  const float att = ((pa0 + pa1) + (pa2 + pa3)) * invZ;

  // store x (coalesced) + stage row in LDS for BN stats
  x[(size_t)b * FEA + lane] = att;
  xblk[wv][lane] = att;
  if (lane < ND) {
    float dv = dx[b * ND + lane];
    x[(size_t)b * FEA + D + lane] = dv;
    xblk[wv][D + lane] = dv;
  }
  __syncthreads();

  // ---- BN partial stats: one thread per feature, 4 rows, bucketed atomics --
  if (t < FEA) {
    float x0 = xblk[0][t], x1 = xblk[1][t], x2 = xblk[2][t], x3 = xblk[3][t];
    float sS = (x0 + x1) + (x2 + x3);
    float sQ = (x0 * x0 + x1 * x1) + (x2 * x2 + x3 * x3);
    const int bkt = (blockIdx.x & 7) * 80 + t;
    atomicAdd(&partS[bkt], sS);
    atomicAdd(&partQ[bkt], sQ);
  }
}

// ------- K2: MLP (4 rows/block, 1024 blocks), pipelined loads + BN ---------
__global__ __launch_bounds__(256) void k_mlp(
    const float* __restrict__ x,
    const float* __restrict__ partS, const float* __restrict__ partQ,
    const float* __restrict__ gamma, const float* __restrict__ beta,
    const float* __restrict__ w1, const float* __restrict__ b1,
    const float* __restrict__ w2, const float* __restrict__ b2,
    const float* __restrict__ w3, const float* __restrict__ b3,
    const float* __restrict__ wf, const float* __restrict__ bf,
    float* __restrict__ out)
{
  __shared__ float scs[80], shs[80];
  __shared__ float xn[MROW][80];
  __shared__ float h1s[MROW][H1];
  __shared__ float h2s[MROW][H2];
  __shared__ float h3s[MROW][H3];
  const int t = threadIdx.x;
  const int b0 = blockIdx.x * MROW;

  if (t < FEA) {
    float S = 0.f, Q = 0.f;
    #pragma unroll
    for (int k = 0; k < 8; ++k) {
      S += partS[k * 80 + t];
      Q += partQ[k * 80 + t];
    }
    float mu  = S * (1.f / BSZ);
    float var = Q * (1.f / BSZ) - mu * mu;
    float scl = gamma[t] * rsqrtf(var + EPSF);
    scs[t] = scl;
    shs[t] = beta[t] - mu * scl;
  }
  __syncthreads();

  for (int k = t; k < MROW * FEA; k += 256) {
    int r = k / FEA, f = k % FEA;
    xn[r][f] = x[(size_t)(b0 + r) * FEA + f] * scs[f] + shs[f];
  }
  __syncthreads();

  // layer 1: 77 -> 256 (thread = output j; 11-deep weight-load batches)
  {
    float acc[MROW];
    const float bb = b1[t];
    #pragma unroll
    for (int r = 0; r < MROW; ++r) acc[r] = bb;
    for (int d0 = 0; d0 < FEA; d0 += 11) {
      float wl[11];
      #pragma unroll
      for (int u = 0; u < 11; ++u) wl[u] = w1[(d0 + u) * H1 + t];
      #pragma unroll
      for (int u = 0; u < 11; ++u)
        #pragma unroll
        for (int r = 0; r < MROW; ++r)
          acc[r] = fmaf(xn[r][d0 + u], wl[u], acc[r]);
    }
    #pragma unroll
    for (int r = 0; r < MROW; ++r) h1s[r][t] = fmaxf(acc[r], 0.f);
  }
  __syncthreads();

  // layer 2: 256 -> 128 (j = t&127, 2 rows per half; 16-deep batches)
  {
    const int j = t & 127;
    const int rb = (t >> 7) * 2;
    float acc0 = b2[j], acc1 = acc0;
    for (int c0 = 0; c0 < H1; c0 += 16) {
      float wl[16];
      #pragma unroll
      for (int u = 0; u < 16; ++u) wl[u] = w2[(c0 + u) * H2 + j];
      #pragma unroll
      for (int u = 0; u < 16; ++u) {
        acc0 = fmaf(h1s[rb + 0][c0 + u], wl[u], acc0);
        acc1 = fmaf(h1s[rb + 1][c0 + u], wl[u], acc1);
      }
    }
    h2s[rb + 0][j] = fmaxf(acc0, 0.f);
    h2s[rb + 1][j] = fmaxf(acc1, 0.f);
  }
  __syncthreads();

  // layer 3: 128 -> 64 (j = t&63, 1 row per quarter; 16-deep batches)
  {
    const int j = t & 63;
    const int r = t >> 6;
    float acc = b3[j];
    for (int c0 = 0; c0 < H2; c0 += 16) {
      float wl[16];
      #pragma unroll
      for (int u = 0; u < 16; ++u) wl[u] = w3[(c0 + u) * H3 + j];
      #pragma unroll
      for (int u = 0; u < 16; ++u)
        acc = fmaf(h2s[r][c0 + u], wl[u], acc);
    }
    h3s[r][j] = fmaxf(acc, 0.f);
  }
  __syncthreads();

  // final: 64 -> 1 + sigmoid (32 threads, 8-lane DPP reduce)
  if (t < MROW * 8) {
    const int r = t >> 3;
    const int g = t & 7;
    float acc = 0.f;
    #pragma unroll
    for (int u = 0; u < 8; ++u)
      acc = fmaf(h3s[r][g * 8 + u], wf[g * 8 + u], acc);
    acc = dpp_add<0xB1>(acc);
    acc = dpp_add<0x4E>(acc);
    acc = dpp_add<0x124>(acc);      // valid at g==0
    if (g == 0)
      out[b0 + r] = 1.f / (1.f + __expf(-(acc + bf[0])));
  }
}

extern "C" void kernel_launch(void* const* d_in, const int* in_sizes, int n_in,
                              void* d_out, int out_size, void* d_ws, size_t ws_size,
                              hipStream_t stream) {
  const int*   sx    = (const int*)  d_in[0];
  const float* dx    = (const float*)d_in[1];
  const float* emb   = (const float*)d_in[2];
  const float* attW  = (const float*)d_in[3];
  const float* attb  = (const float*)d_in[4];
  const float* attdW = (const float*)d_in[5];
  const float* attdb = (const float*)d_in[6];
  const float* gamma = (const float*)d_in[7];
  const float* beta  = (const float*)d_in[8];
  const float* w1    = (const float*)d_in[9];
  const float* b1    = (const float*)d_in[10];
  const float* w2    = (const float*)d_in[11];
  const float* b2    = (const float*)d_in[12];
  const float* w3    = (const float*)d_in[13];
  const float* b3    = (const float*)d_in[14];
  const float* wf    = (const float*)d_in[15];
  const float* bf    = (const float*)d_in[16];
  float* out = (float*)d_out;

  float* x     = (float*)d_ws;                    // B*FEA
  float* partS = x + (size_t)BSZ * FEA;           // 8*80
  float* partQ = partS + 8 * 80;                  // 8*80

  hipMemsetAsync(partS, 0, 2 * 8 * 80 * sizeof(float), stream);
  k_attn<<<BSZ / 4, 256, 0, stream>>>(sx, dx, emb, attW, attb, attdW, attdb,
                                      x, partS, partQ);
  k_mlp<<<BSZ / 4, 256, 0, stream>>>(x, partS, partQ, gamma, beta,
                                     w1, b1, w2, b2, w3, b3, wf, bf, out);
}